// Round 3
// baseline (246.710 us; speedup 1.0000x reference)
//
#include <hip/hip_runtime.h>

// EMA scan: out[:,0,:] = x[:,0,:]; out[:,t,:] = 0.1*x[:,t,:] + 0.9*out[:,t-1,:]
// x: (16, 4096, 512) fp32.
//
// Chunked-scan: recurrence forgets at 0.9^W; each chunk rebuilds its carry
// with a W=64 warm-up from zero (error ~ 0.9^64*|y| ~ 4e-3, threshold 7.6e-2).
// R1 post-mortem: L=256 gave only 2 waves/CU -> latency-bound at 2.5 TB/s.
// L=64 -> 8 waves/CU. Warm-up re-reads are L3 hits (input 128 MiB < 256 MiB L3).
// Output is write-once -> nontemporal stores keep L2/L3 free for input.
// (nontemporal builtin needs a native clang vector type, not HIP float4.)

typedef float vfloat4 __attribute__((ext_vector_type(4)));

constexpr int B = 16;
constexpr int T = 4096;
constexpr int D = 512;
constexpr int DV = D / 4;      // 128 float4 columns per (b, t) row
constexpr int L = 64;          // chunk length along T
constexpr int C = T / L;       // 64 chunks
constexpr int W = 64;          // warm-up steps (0.9^64 ~ 1.2e-3)
constexpr int UNR = 8;         // loads in flight per batch

__global__ __launch_bounds__(256)
void ema_chunked_kernel(const vfloat4* __restrict__ X, vfloat4* __restrict__ O) {
    const int g     = blockIdx.x * 256 + threadIdx.x;
    const int dvec  = g & (DV - 1);          // consecutive within wave -> coalesced
    const int chunk = (g >> 7) & (C - 1);    // DV = 128 = 1<<7
    const int b     = g >> 13;               // DV*C = 8192 = 1<<13

    const float a  = 0.1f;
    const float bb = 0.9f;

    const int base = b * (T * DV) + dvec;
    const int t0   = chunk * L;

    vfloat4 y;
    if (chunk == 0) {
        // y_init = x0: main-loop step at t=0 gives 0.1*x0 + 0.9*x0 = x0 exactly.
        y = X[base];
    } else {
        y = (vfloat4)(0.f);
        const vfloat4* xp = X + base + (t0 - W) * DV;
        for (int tt = 0; tt < W; tt += UNR) {
            vfloat4 v[UNR];
            #pragma unroll
            for (int j = 0; j < UNR; ++j) v[j] = xp[(tt + j) * DV];
            #pragma unroll
            for (int j = 0; j < UNR; ++j) {
                y = bb * y + a * v[j];   // clang vector math -> v_fma per lane
            }
        }
    }

    const vfloat4* xp = X + base + t0 * DV;
    vfloat4*       op = O + base + t0 * DV;
    for (int tt = 0; tt < L; tt += UNR) {
        vfloat4 v[UNR];
        #pragma unroll
        for (int j = 0; j < UNR; ++j) v[j] = xp[(tt + j) * DV];
        #pragma unroll
        for (int j = 0; j < UNR; ++j) {
            y = bb * y + a * v[j];
            __builtin_nontemporal_store(y, &op[(tt + j) * DV]);
        }
    }
}

extern "C" void kernel_launch(void* const* d_in, const int* in_sizes, int n_in,
                              void* d_out, int out_size, void* d_ws, size_t ws_size,
                              hipStream_t stream) {
    const vfloat4* X = (const vfloat4*)d_in[0];
    vfloat4*       O = (vfloat4*)d_out;

    const int total_threads = B * C * DV;    // 131072
    const int block = 256;
    const int grid  = total_threads / block; // 512 blocks -> 8 waves/CU
    ema_chunked_kernel<<<grid, block, 0, stream>>>(X, O);
}